// Round 1
// baseline (344.269 us; speedup 1.0000x reference)
//
#include <hip/hip_runtime.h>

// AdditiveAttention: B=8, Q=128, V=512, H=512.
// out = [context (B*Q*H) | weights (B*Q*V)] fp32, each 524288 elements.
// ws layout: qp [1024*512] f32 @0, vp [4096*512] f32 @2MB  (10MB total).
// bc is dropped: softmax is shift-invariant and scores are never output.

#define NEG_INF (-__builtin_inff())

__device__ __forceinline__ float fast_tanh(float x) {
  // tanh(x) = 1 - 2/(exp(2x)+1); exp(2x) = exp2(x*2*log2(e))
  float e = exp2f(x * 2.8853900817779268f);
  float r = __builtin_amdgcn_rcpf(e + 1.0f);
  return __builtin_fmaf(-2.0f, r, 1.0f);
}

// out[m][n] = sum_k A[m][k] * W[n][k] + bias[n];  N=K=512, M % 64 == 0.
// Both A and W are K-contiguous -> identical staging for both operands.
__global__ __launch_bounds__(256) void proj_gemm(
    const float* __restrict__ A, const float* __restrict__ W,
    const float* __restrict__ bias, float* __restrict__ out)
{
  __shared__ __align__(16) float As[16][68]; // [k][m], pad 68 (16B-aligned rows, no write conflicts)
  __shared__ __align__(16) float Ws[16][68]; // [k][n]
  const int t  = threadIdx.x;
  const int tx = t & 15, ty = t >> 4;          // 16x16 threads, 4x4 microtile
  const int m0 = blockIdx.y << 6, n0 = blockIdx.x << 6;
  const int row = t >> 2;                      // 0..63
  const int kq  = (t & 3) << 2;                // 0,4,8,12

  const float* Ap = A + (size_t)(m0 + row) * 512 + kq;
  const float* Wp = W + (size_t)(n0 + row) * 512 + kq;

  float acc[4][4] = {};
  float4 a = *(const float4*)(Ap);
  float4 w = *(const float4*)(Wp);

  for (int k0 = 0; k0 < 512; k0 += 16) {
    __syncthreads();
    As[kq+0][row]=a.x; As[kq+1][row]=a.y; As[kq+2][row]=a.z; As[kq+3][row]=a.w;
    Ws[kq+0][row]=w.x; Ws[kq+1][row]=w.y; Ws[kq+2][row]=w.z; Ws[kq+3][row]=w.w;
    __syncthreads();
    if (k0 + 16 < 512) {            // prefetch next tile (latency hidden under compute)
      a = *(const float4*)(Ap + k0 + 16);
      w = *(const float4*)(Wp + k0 + 16);
    }
#pragma unroll
    for (int kk = 0; kk < 16; ++kk) {
      float4 av = *(const float4*)&As[kk][ty << 2]; // broadcast across tx
      float4 wv = *(const float4*)&Ws[kk][tx << 2]; // contiguous 256B across 16 lanes
      float am[4] = {av.x, av.y, av.z, av.w};
      float wn[4] = {wv.x, wv.y, wv.z, wv.w};
#pragma unroll
      for (int i = 0; i < 4; ++i)
#pragma unroll
        for (int j = 0; j < 4; ++j)
          acc[i][j] = __builtin_fmaf(am[i], wn[j], acc[i][j]);
    }
  }
  float4 bi = *(const float4*)(bias + n0 + (tx << 2));
  float bn[4] = {bi.x, bi.y, bi.z, bi.w};
#pragma unroll
  for (int i = 0; i < 4; ++i) {
    float4 o;
    o.x = acc[i][0] + bn[0]; o.y = acc[i][1] + bn[1];
    o.z = acc[i][2] + bn[2]; o.w = acc[i][3] + bn[3];
    *(float4*)(out + (size_t)(m0 + (ty << 2) + i) * 512 + n0 + (tx << 2)) = o;
  }
}

// One block = (b, 4 consecutive q). 256 threads; wave w owns q = q0 + w.
// Lane l owns v = 8l..8l+7 (scores/weights) and h = 8l..8l+7 (context).
__global__ __launch_bounds__(256) void attn_fused(
    const float* __restrict__ qp, const float* __restrict__ vp,
    const float* __restrict__ values, const int* __restrict__ mask,
    const float* __restrict__ wc,
    float* __restrict__ out_ctx, float* __restrict__ out_w)
{
  __shared__ __align__(16) float qps[4][512];
  __shared__ __align__(16) float wcs[512];
  __shared__ __align__(16) float vps[16][516]; // [h][v], pad 516 (16B-aligned rows, conflict-free)
  __shared__ __align__(16) float wls[4][512];

  const int t    = threadIdx.x;
  const int lane = t & 63;
  const int qh   = t >> 6;                 // wave id = which q
  const int b    = blockIdx.x >> 5;
  const int q0   = (blockIdx.x & 31) << 2;

  { // stage qp rows (bias already folded in) + wc
    const float4* src = (const float4*)(qp + (size_t)(b * 128 + q0) * 512);
    float4* dst = (float4*)&qps[0][0];
    dst[t]       = src[t];
    dst[t + 256] = src[t + 256];
    if (t < 128) ((float4*)wcs)[t] = ((const float4*)wc)[t];
  }

  float acc[8] = {0,0,0,0,0,0,0,0};
  const float* vpb = vp + (size_t)b * 512 * 512;

  // prefetch chunk 0: thread t loads 8 float4s; slot idx -> (v = idx/4, kquad = idx%4)
  float4 pf[8];
#pragma unroll
  for (int i = 0; i < 8; ++i) {
    int idx = t + (i << 8);
    int v = idx >> 2, kq = (idx & 3) << 2;
    pf[i] = *(const float4*)(vpb + (size_t)v * 512 + kq);
  }

  for (int hc = 0; hc < 512; hc += 16) {
    __syncthreads();                       // previous chunk's reads complete
#pragma unroll
    for (int i = 0; i < 8; ++i) {          // transpose-write into [h][v]
      int idx = t + (i << 8);
      int v = idx >> 2, kq = (idx & 3) << 2;
      vps[kq+0][v] = pf[i].x; vps[kq+1][v] = pf[i].y;
      vps[kq+2][v] = pf[i].z; vps[kq+3][v] = pf[i].w;
    }
    __syncthreads();
    if (hc + 16 < 512) {                   // prefetch next chunk under compute
#pragma unroll
      for (int i = 0; i < 8; ++i) {
        int idx = t + (i << 8);
        int v = idx >> 2, kq = (idx & 3) << 2;
        pf[i] = *(const float4*)(vpb + (size_t)v * 512 + hc + 16 + kq);
      }
    }
#pragma unroll 4
    for (int h = 0; h < 16; ++h) {
      float qv  = qps[qh][hc + h];         // wave-uniform broadcast
      float wch = wcs[hc + h];
      float4 p0 = *(const float4*)&vps[h][lane << 3];
      float4 p1 = *(const float4*)&vps[h][(lane << 3) + 4];
      float xs[8] = {p0.x,p0.y,p0.z,p0.w,p1.x,p1.y,p1.z,p1.w};
#pragma unroll
      for (int k = 0; k < 8; ++k)
        acc[k] = __builtin_fmaf(fast_tanh(qv + xs[k]), wch, acc[k]);
    }
  }

  // mask -> -inf
  {
    const int4* mb = (const int4*)(mask + b * 512 + (lane << 3));
    int4 m0 = mb[0], m1 = mb[1];
    int mks[8] = {m0.x,m0.y,m0.z,m0.w,m1.x,m1.y,m1.z,m1.w};
#pragma unroll
    for (int k = 0; k < 8; ++k) if (mks[k] == 0) acc[k] = NEG_INF;
  }

  // per-wave softmax over v (wave qh holds all 512 scores of its q)
  float m = acc[0];
#pragma unroll
  for (int k = 1; k < 8; ++k) m = fmaxf(m, acc[k]);
#pragma unroll
  for (int off = 32; off > 0; off >>= 1) m = fmaxf(m, __shfl_xor(m, off, 64));
  float e[8], s = 0.0f;
#pragma unroll
  for (int k = 0; k < 8; ++k) { e[k] = exp2f((acc[k] - m) * 1.4426950408889634f); s += e[k]; }
#pragma unroll
  for (int off = 32; off > 0; off >>= 1) s += __shfl_xor(s, off, 64);
  float inv = __builtin_amdgcn_rcpf(s);

  float4 w0 = {e[0]*inv, e[1]*inv, e[2]*inv, e[3]*inv};
  float4 w1 = {e[4]*inv, e[5]*inv, e[6]*inv, e[7]*inv};
  *(float4*)&wls[qh][lane << 3]       = w0;  // same-wave producer/consumer: no barrier needed
  *(float4*)&wls[qh][(lane << 3) + 4] = w1;
  {
    float* ow = out_w + (size_t)(b * 128 + q0 + qh) * 512 + (lane << 3);
    *(float4*)ow       = w0;
    *(float4*)(ow + 4) = w1;
  }

  // context[q][h] = sum_v w[v] * values[b][v][h]; lane l owns h = 8l..8l+7
  float c[8] = {0,0,0,0,0,0,0,0};
  const float* vb = values + (size_t)b * 512 * 512 + (lane << 3);
  for (int v = 0; v < 512; ++v) {
    float wv = wls[qh][v];                 // wave-uniform broadcast
    if (wv != 0.0f) {                      // uniform branch: skip masked v (saves ~half traffic)
      const float4 r0 = *(const float4*)(vb + (size_t)v * 512);
      const float4 r1 = *(const float4*)(vb + (size_t)v * 512 + 4);
      c[0] = __builtin_fmaf(wv, r0.x, c[0]); c[1] = __builtin_fmaf(wv, r0.y, c[1]);
      c[2] = __builtin_fmaf(wv, r0.z, c[2]); c[3] = __builtin_fmaf(wv, r0.w, c[3]);
      c[4] = __builtin_fmaf(wv, r1.x, c[4]); c[5] = __builtin_fmaf(wv, r1.y, c[5]);
      c[6] = __builtin_fmaf(wv, r1.z, c[6]); c[7] = __builtin_fmaf(wv, r1.w, c[7]);
    }
  }
  float* oc = out_ctx + (size_t)(b * 128 + q0 + qh) * 512 + (lane << 3);
  float4 c0 = {c[0], c[1], c[2], c[3]};
  float4 c1 = {c[4], c[5], c[6], c[7]};
  *(float4*)oc       = c0;
  *(float4*)(oc + 4) = c1;
}

extern "C" void kernel_launch(void* const* d_in, const int* in_sizes, int n_in,
                              void* d_out, int out_size, void* d_ws, size_t ws_size,
                              hipStream_t stream) {
  const float* query  = (const float*)d_in[0];
  const float* values = (const float*)d_in[1];
  const int*   mask   = (const int*)d_in[2];
  const float* Wq     = (const float*)d_in[3];
  const float* bq     = (const float*)d_in[4];
  const float* Wv     = (const float*)d_in[5];
  const float* bv     = (const float*)d_in[6];
  const float* wc     = (const float*)d_in[7];
  // d_in[8] = bc: provably no effect on outputs (softmax shift-invariance) -> dropped.

  float* out   = (float*)d_out;
  float* qp    = (float*)d_ws;            // 1024 x 512
  float* vp    = qp + (size_t)1024 * 512; // 4096 x 512

  proj_gemm<<<dim3(8, 16), 256, 0, stream>>>(query,  Wq, bq, qp);
  proj_gemm<<<dim3(8, 64), 256, 0, stream>>>(values, Wv, bv, vp);
  attn_fused<<<256, 256, 0, stream>>>(qp, vp, values, mask, wc,
                                      out, out + (size_t)8 * 128 * 512);
}

// Round 2
// 236.452 us; speedup vs baseline: 1.4560x; 1.4560x over previous
//
#include <hip/hip_runtime.h>

// AdditiveAttention: B=8, Q=128, V=512, H=512.
// out = [context (B*Q*H) | weights (B*Q*V)] fp32.
// ws: qp [1024*512] f32 @0, vp [4096*512] f32 @2MB (exactly 10MB - no growth).
// bc dropped (softmax shift-invariant); sum_h wc[h] term also cancels in softmax.

#define NEG_INF (-__builtin_inff())
#define C_SCALE 2.8853900817779268f   // 2*log2(e): x_pre = C*(qp+vp) so exp(2y)=2^x
#define K_SCALE 1.4426950408889634f   // log2(e)

// ---------------- projections: out[m][n] = sum_k A[m][k]*W[n][k] + bias[n] ----
// Combined qp+vp GEMM in one launch: by<16 -> query block, else values block.
__global__ __launch_bounds__(256) void proj_gemm2(
    const float* __restrict__ query, const float* __restrict__ values,
    const float* __restrict__ Wq, const float* __restrict__ Wv,
    const float* __restrict__ bq, const float* __restrict__ bv,
    float* __restrict__ qp, float* __restrict__ vp)
{
  __shared__ __align__(16) float As[16][68];
  __shared__ __align__(16) float Ws[16][68];
  const int t  = threadIdx.x;
  const int tx = t & 15, ty = t >> 4;
  const int by = blockIdx.y;
  const bool isQ = (by < 16);
  const float* A    = isQ ? query : values;
  const float* W    = isQ ? Wq : Wv;
  const float* bias = isQ ? bq : bv;
  float*       out  = isQ ? qp : vp;
  const int m0 = (isQ ? by : (by - 16)) << 6;
  const int n0 = blockIdx.x << 6;
  const int row = t >> 2;
  const int kq  = (t & 3) << 2;

  const float* Ap = A + (size_t)(m0 + row) * 512 + kq;
  const float* Wp = W + (size_t)(n0 + row) * 512 + kq;

  float acc[4][4] = {};
  float4 a = *(const float4*)(Ap);
  float4 w = *(const float4*)(Wp);

  for (int k0 = 0; k0 < 512; k0 += 16) {
    __syncthreads();
    As[kq+0][row]=a.x; As[kq+1][row]=a.y; As[kq+2][row]=a.z; As[kq+3][row]=a.w;
    Ws[kq+0][row]=w.x; Ws[kq+1][row]=w.y; Ws[kq+2][row]=w.z; Ws[kq+3][row]=w.w;
    __syncthreads();
    if (k0 + 16 < 512) {
      a = *(const float4*)(Ap + k0 + 16);
      w = *(const float4*)(Wp + k0 + 16);
    }
#pragma unroll
    for (int kk = 0; kk < 16; ++kk) {
      float4 av = *(const float4*)&As[kk][ty << 2];
      float4 wv = *(const float4*)&Ws[kk][tx << 2];
      float am[4] = {av.x, av.y, av.z, av.w};
      float wn[4] = {wv.x, wv.y, wv.z, wv.w};
#pragma unroll
      for (int i = 0; i < 4; ++i)
#pragma unroll
        for (int j = 0; j < 4; ++j)
          acc[i][j] = __builtin_fmaf(am[i], wn[j], acc[i][j]);
    }
  }
  float4 bi = *(const float4*)(bias + n0 + (tx << 2));
  float bn[4] = {bi.x, bi.y, bi.z, bi.w};
#pragma unroll
  for (int i = 0; i < 4; ++i) {
    float4 o;
    o.x = acc[i][0] + bn[0]; o.y = acc[i][1] + bn[1];
    o.z = acc[i][2] + bn[2]; o.w = acc[i][3] + bn[3];
    *(float4*)(out + (size_t)(m0 + (ty << 2) + i) * 512 + n0 + (tx << 2)) = o;
  }
}

// ---------------- fused attention -------------------------------------------
// Block = (b, 4 q's), 1024 threads = 16 waves. wave w: q = w>>2, part = w&3.
// In-block mask compaction: only unmasked v's (cnt ~ 256) get tanh/softmax work.
// Score phase: 4 waves per q split compacted v-range; softmax combined via LDS.
// Context phase: 4 waves per q split the h-range (each covers all v-slots).
// b = blockIdx.x & 7 -> all 32 blocks of a batch land on one XCD (L2 locality).
__global__ __launch_bounds__(1024) void attn_fused(
    const float* __restrict__ qp, const float* __restrict__ vp,
    const float* __restrict__ values, const int* __restrict__ mask,
    const float* __restrict__ wc,
    float* __restrict__ out_ctx, float* __restrict__ out_w)
{
  __shared__ __align__(16) float qps[4][512];     // pre-scaled by C
  __shared__ __align__(16) float wcs[512];
  __shared__ __align__(16) float vps[16][516];    // score: [h][slot]*C; ctx: [slot][h]
  __shared__ __align__(16) float wls[4][512];     // weights by compacted slot
  __shared__ int   idxs[512];                     // compacted v indices (pad 0)
  __shared__ int   cnt8[8];
  __shared__ float red_m[4][4], red_s[4][4];

  const int t    = threadIdx.x;
  const int lane = t & 63;
  const int w    = t >> 6;
  const int q    = w >> 2;
  const int part = w & 3;
  const int b    = blockIdx.x & 7;
  const int q0   = (blockIdx.x >> 3) << 2;

  // ---- setup: stage qps (scaled) + wc, zero idxs, zero out_w, ballot masks
  if (t < 512) {
    float4 v4 = ((const float4*)(qp + (size_t)(b * 128 + q0) * 512))[t];
    v4.x *= C_SCALE; v4.y *= C_SCALE; v4.z *= C_SCALE; v4.w *= C_SCALE;
    ((float4*)qps)[t] = v4;
    idxs[t] = 0;
    float4 z = {0.f, 0.f, 0.f, 0.f};
    ((float4*)(out_w + (size_t)(b * 128 + q0) * 512))[t] = z;
  } else if (t < 640) {
    ((float4*)wcs)[t - 512] = ((const float4*)wc)[t - 512];
  }
  unsigned long long bal = 0; int mv = 0;
  if (w < 8) {
    mv  = mask[b * 512 + (w << 6) + lane];
    bal = __ballot(mv != 0);
    if (lane == 0) cnt8[w] = __popcll(bal);
  }
  __syncthreads();
  int cnt = 0, offw = 0;
#pragma unroll
  for (int j = 0; j < 8; ++j) { if (j == w) offw = cnt; cnt += cnt8[j]; }
  if (w < 8 && mv) {
    int rank = __popcll(bal & ((1ull << lane) - 1ull));
    idxs[offw + rank] = (w << 6) + lane;
  }
  __syncthreads();

  // ---- score phase: acc = sum_h wc[h] * 1/(2^(C*(qp+vp)) + 1)
  const int  SP  = (cnt > 256) ? 128 : 64;   // slots per wave-part
  const bool two = (SP == 128);
  const float* vpb = vp + (size_t)b * 512 * 512;
  const int sslot = t >> 2;            // 0..255 (staging slot)
  const int kq    = (t & 3) << 2;      // h-quad within chunk

  int   row0 = idxs[sslot];
  int   row1 = two ? idxs[sslot + 256] : 0;
  float4 pf0 = *(const float4*)(vpb + (size_t)row0 * 512 + kq);
  float4 pf1 = {0,0,0,0};
  if (two) pf1 = *(const float4*)(vpb + (size_t)row1 * 512 + kq);

  float acc0 = 0.f, acc1 = 0.f;
  const int s0 = part * SP + lane;
  const int s1 = s0 + 64;

  for (int hc = 0; hc < 512; hc += 16) {
    __syncthreads();                            // prior chunk's reads done
    vps[kq+0][sslot] = pf0.x * C_SCALE; vps[kq+1][sslot] = pf0.y * C_SCALE;
    vps[kq+2][sslot] = pf0.z * C_SCALE; vps[kq+3][sslot] = pf0.w * C_SCALE;
    if (two) {
      vps[kq+0][sslot+256] = pf1.x * C_SCALE; vps[kq+1][sslot+256] = pf1.y * C_SCALE;
      vps[kq+2][sslot+256] = pf1.z * C_SCALE; vps[kq+3][sslot+256] = pf1.w * C_SCALE;
    }
    __syncthreads();
    if (hc + 16 < 512) {                        // prefetch next chunk
      pf0 = *(const float4*)(vpb + (size_t)row0 * 512 + hc + 16 + kq);
      if (two) pf1 = *(const float4*)(vpb + (size_t)row1 * 512 + hc + 16 + kq);
    }
    float4 qv[4], wv[4];
#pragma unroll
    for (int i = 0; i < 4; ++i) {
      qv[i] = *(const float4*)&qps[q][hc + (i << 2)];   // wave-uniform broadcast
      wv[i] = *(const float4*)&wcs[hc + (i << 2)];
    }
    const float* qf = (const float*)qv;
    const float* wf = (const float*)wv;
#pragma unroll
    for (int h = 0; h < 16; ++h) {
      float e0 = exp2f(qf[h] + vps[h][s0]);             // stride-1: conflict-free
      float r0 = __builtin_amdgcn_rcpf(e0 + 1.0f);
      acc0 = __builtin_fmaf(wf[h], r0, acc0);
      if (two) {
        float e1 = exp2f(qf[h] + vps[h][s1]);
        float r1 = __builtin_amdgcn_rcpf(e1 + 1.0f);
        acc1 = __builtin_fmaf(wf[h], r1, acc1);
      }
    }
  }

  // ---- softmax over compacted slots (score_k = -2*K*acc, shift-const dropped)
  float sck0 = (s0 < cnt) ? -C_SCALE * acc0 : NEG_INF;
  float sck1 = (two && s1 < cnt) ? -C_SCALE * acc1 : NEG_INF;
  float m = fmaxf(sck0, sck1);
#pragma unroll
  for (int off = 32; off > 0; off >>= 1) m = fmaxf(m, __shfl_xor(m, off, 64));
  m = fmaxf(m, -3.0e38f);                       // guard all-invalid part
  float e0 = exp2f(sck0 - m);
  float e1 = two ? exp2f(sck1 - m) : 0.f;
  float s = e0 + e1;
#pragma unroll
  for (int off = 32; off > 0; off >>= 1) s += __shfl_xor(s, off, 64);
  if (lane == 0) { red_m[q][part] = m; red_s[q][part] = s; }
  __syncthreads();
  float M = fmaxf(fmaxf(red_m[q][0], red_m[q][1]), fmaxf(red_m[q][2], red_m[q][3]));
  float S = red_s[q][0] * exp2f(red_m[q][0] - M) + red_s[q][1] * exp2f(red_m[q][1] - M)
          + red_s[q][2] * exp2f(red_m[q][2] - M) + red_s[q][3] * exp2f(red_m[q][3] - M);
  float scale = exp2f(m - M) * __builtin_amdgcn_rcpf(S);
  float w0 = e0 * scale, w1 = e1 * scale;

  float* owq = out_w + (size_t)(b * 128 + q0 + q) * 512;
  wls[q][s0] = w0;
  if (s0 < cnt) owq[idxs[s0]] = w0;             // scatter (masked stay 0)
  if (two) {
    wls[q][s1] = w1;
    if (s1 < cnt) owq[idxs[s1]] = w1;
  }
  __syncthreads();                              // wls ready; vps free for reuse

  // ---- context: wave (q, part) covers h-range [part*128, part*128+128)
  const int NCH = (cnt + 15) >> 4;
  const int h0 = part * 128 + lane, h1 = h0 + 64;
  const float* vb = values + (size_t)b * 512 * 512;
  const int jr = t >> 6, cc = (t & 63) << 2;    // staging: row jr, col quad cc
  int vrow = idxs[jr];
  float4 pa = *(const float4*)(vb + (size_t)vrow * 512 + cc);
  float4 pb = *(const float4*)(vb + (size_t)vrow * 512 + cc + 256);
  float c0 = 0.f, c1 = 0.f;

  for (int ch = 0; ch < NCH; ++ch) {
    __syncthreads();
    *(float4*)&vps[jr][cc]       = pa;
    *(float4*)&vps[jr][cc + 256] = pb;
    __syncthreads();
    if (ch + 1 < NCH) {
      vrow = idxs[(ch + 1) * 16 + jr];
      pa = *(const float4*)(vb + (size_t)vrow * 512 + cc);
      pb = *(const float4*)(vb + (size_t)vrow * 512 + cc + 256);
    }
#pragma unroll
    for (int jj = 0; jj < 16; ++jj) {
      float wv = wls[q][(ch << 4) + jj];        // wave-uniform broadcast
      c0 = __builtin_fmaf(wv, vps[jj][h0], c0); // stride-1: conflict-free
      c1 = __builtin_fmaf(wv, vps[jj][h1], c1);
    }
  }
  float* ocq = out_ctx + (size_t)(b * 128 + q0 + q) * 512;
  ocq[h0] = c0;
  ocq[h1] = c1;
}

extern "C" void kernel_launch(void* const* d_in, const int* in_sizes, int n_in,
                              void* d_out, int out_size, void* d_ws, size_t ws_size,
                              hipStream_t stream) {
  const float* query  = (const float*)d_in[0];
  const float* values = (const float*)d_in[1];
  const int*   mask   = (const int*)d_in[2];
  const float* Wq     = (const float*)d_in[3];
  const float* bq     = (const float*)d_in[4];
  const float* Wv     = (const float*)d_in[5];
  const float* bv     = (const float*)d_in[6];
  const float* wc     = (const float*)d_in[7];
  // d_in[8] = bc: no effect on outputs (softmax shift-invariance) -> dropped.

  float* out = (float*)d_out;
  float* qp  = (float*)d_ws;                 // 1024 x 512
  float* vp  = qp + (size_t)1024 * 512;      // 4096 x 512

  proj_gemm2<<<dim3(8, 80), 256, 0, stream>>>(query, values, Wq, Wv, bq, bv, qp, vp);
  attn_fused<<<256, 1024, 0, stream>>>(qp, vp, values, mask, wc,
                                       out, out + (size_t)8 * 128 * 512);
}

// Round 3
// 151.966 us; speedup vs baseline: 2.2654x; 1.5560x over previous
//
#include <hip/hip_runtime.h>
#include <hip/hip_bf16.h>

// AdditiveAttention: B=8, Q=128, V=512, H=512.
// out = [context (B*Q*H) | weights (B*Q*V)] fp32.
// ws: qp [1024*512] f32 @0, vp [4096*512] f32 @2MB (10MB).
// bc dropped (softmax shift-invariant); sum_h wc[h] const also cancels.
// Score math (verified R1/R2): tanh(y)=1-2r, r=1/(2^(C*y)+1), C=2*log2(e);
//   softmax arg = -C * sum_h wc[h]*r  (consts dropped).

#define C_SCALE 2.8853900817779268f

typedef __attribute__((ext_vector_type(8))) short short8;
typedef __attribute__((ext_vector_type(4))) float f32x4;

__device__ __forceinline__ float fexp2(float x) { return __builtin_amdgcn_exp2f(x); }
__device__ __forceinline__ float frcp(float x)  { return __builtin_amdgcn_rcpf(x); }
__device__ __forceinline__ short f2bf(float x) {
  __hip_bfloat16 h = __float2bfloat16(x);
  return __builtin_bit_cast(short, h);
}
__device__ __forceinline__ float bf2f(short s) {
  return __bfloat162float(__builtin_bit_cast(__hip_bfloat16, s));
}

// ---------------- split-bf16 MFMA GEMM ---------------------------------------
// out[m][n] = sum_k A[m][k]*W[n][k] + bias[n].  N=K=512.
// x = hi + lo (both bf16); D = Ahi*Whi + Ahi*Wlo + Alo*Whi (lo*lo ~2^-16, dropped).
// 64x64 tile, KC=64. by<16 -> query rows (qp), else values rows (vp).
// LDS rows padded to 72 shorts (144B): b128 frag reads land 8 lanes/4-bank
// group = stride-1-equivalent (~12cyc), vs 16-way unpadded.
__global__ __launch_bounds__(256) void proj_gemm_mfma(
    const float* __restrict__ query, const float* __restrict__ values,
    const float* __restrict__ Wq, const float* __restrict__ Wv,
    const float* __restrict__ bq, const float* __restrict__ bv,
    float* __restrict__ qp, float* __restrict__ vp)
{
  __shared__ short sAhi[64 * 72];
  __shared__ short sAlo[64 * 72];
  __shared__ short sWhi[64 * 72];
  __shared__ short sWlo[64 * 72];

  const int t    = threadIdx.x;
  const int lane = t & 63;
  const int w    = t >> 6;                  // wave 0..3
  const int by   = blockIdx.y;
  const bool isQ = (by < 16);
  const float* A    = isQ ? query : values;
  const float* W    = isQ ? Wq : Wv;
  const float* bias = isQ ? bq : bv;
  float*       out  = isQ ? qp : vp;
  const int m0 = (isQ ? by : (by - 16)) << 6;
  const int n0 = blockIdx.x << 6;

  // staging map: thread t, iter p: row = t>>2 (64 rows), f4-col = p*4 + (t&3)
  const int srow = t >> 2, scol = t & 3;
  const float* Ap = A + (size_t)(m0 + srow) * 512 + (scol << 2);
  const float* Wp = W + (size_t)(n0 + srow) * 512 + (scol << 2);

  const int mw = (w & 1) << 5, nw = (w >> 1) << 5;   // wave's 32x32 quadrant
  const int frow = lane & 15, fquad = lane >> 4;

  f32x4 acc[2][2] = {};
  float4 pfA[4], pfW[4];
#pragma unroll
  for (int p = 0; p < 4; ++p) {
    pfA[p] = *(const float4*)(Ap + (p << 4));
    pfW[p] = *(const float4*)(Wp + (p << 4));
  }

  for (int kc = 0; kc < 512; kc += 64) {
    __syncthreads();
#pragma unroll
    for (int p = 0; p < 4; ++p) {
      float av[4] = {pfA[p].x, pfA[p].y, pfA[p].z, pfA[p].w};
      float wv[4] = {pfW[p].x, pfW[p].y, pfW[p].z, pfW[p].w};
      short4 ah, al, wh, wl;
      short* ahp = (short*)&ah; short* alp = (short*)&al;
      short* whp = (short*)&wh; short* wlp = (short*)&wl;
#pragma unroll
      for (int k = 0; k < 4; ++k) {
        short h1 = f2bf(av[k]); ahp[k] = h1; alp[k] = f2bf(av[k] - bf2f(h1));
        short h2 = f2bf(wv[k]); whp[k] = h2; wlp[k] = f2bf(wv[k] - bf2f(h2));
      }
      const int ofs = srow * 72 + ((p << 2) + scol) * 4;
      *(short4*)&sAhi[ofs] = ah; *(short4*)&sAlo[ofs] = al;
      *(short4*)&sWhi[ofs] = wh; *(short4*)&sWlo[ofs] = wl;
    }
    __syncthreads();
    if (kc + 64 < 512) {
#pragma unroll
      for (int p = 0; p < 4; ++p) {
        pfA[p] = *(const float4*)(Ap + kc + 64 + (p << 4));
        pfW[p] = *(const float4*)(Wp + kc + 64 + (p << 4));
      }
    }
#pragma unroll
    for (int kb = 0; kb < 2; ++kb) {
      const int ko = kb * 32 + fquad * 8;
      short8 ahi[2], alo[2], whi[2], wlo[2];
#pragma unroll
      for (int mt = 0; mt < 2; ++mt) {
        const int r = (mw + mt * 16 + frow) * 72 + ko;
        ahi[mt] = *(const short8*)&sAhi[r];
        alo[mt] = *(const short8*)&sAlo[r];
      }
#pragma unroll
      for (int nt = 0; nt < 2; ++nt) {
        const int r = (nw + nt * 16 + frow) * 72 + ko;
        whi[nt] = *(const short8*)&sWhi[r];
        wlo[nt] = *(const short8*)&sWlo[r];
      }
#pragma unroll
      for (int mt = 0; mt < 2; ++mt)
#pragma unroll
        for (int nt = 0; nt < 2; ++nt) {
          acc[mt][nt] = __builtin_amdgcn_mfma_f32_16x16x32_bf16(
              alo[mt], whi[nt], acc[mt][nt], 0, 0, 0);
          acc[mt][nt] = __builtin_amdgcn_mfma_f32_16x16x32_bf16(
              ahi[mt], wlo[nt], acc[mt][nt], 0, 0, 0);
          acc[mt][nt] = __builtin_amdgcn_mfma_f32_16x16x32_bf16(
              ahi[mt], whi[nt], acc[mt][nt], 0, 0, 0);
        }
    }
  }

  // epilogue: C/D layout col = lane&15, row = (lane>>4)*4 + reg
#pragma unroll
  for (int nt = 0; nt < 2; ++nt) {
    const int n = n0 + nw + nt * 16 + frow;
    const float bn = bias[n];
#pragma unroll
    for (int mt = 0; mt < 2; ++mt) {
      float vreg[4] = {acc[mt][nt].x, acc[mt][nt].y, acc[mt][nt].z, acc[mt][nt].w};
#pragma unroll
      for (int r = 0; r < 4; ++r) {
        const int m = m0 + mw + mt * 16 + fquad * 4 + r;
        out[(size_t)m * 512 + n] = vreg[r] + bn;
      }
    }
  }
}

// ---------------- fused attention (no-LDS dataflow) --------------------------
// Block = (b, 2 q's), 512 threads = 8 waves; grid 512 = 2 blocks/CU.
// Every wave computes BOTH q's (one vp read serves 2 q's).
// Score: wave w owns slots [w*4*NSTEP, ...); lane = (slot-group g = lane>>4,
//   h-quad = lane&15). vp read direct from global (L1/L2; vp[b]+values[b] =
//   2MB pinned per XCD via blockIdx&7 = b swizzle). Per-slot reduce: 4
//   butterflies over the 16 lanes sharing g. No LDS in hot loops.
// Context: wave w owns h-window [w*64, w*64+64); all slots; butterfly over g.
__global__ __launch_bounds__(512) void attn_fused(
    const float* __restrict__ qp, const float* __restrict__ vp,
    const float* __restrict__ values, const int* __restrict__ mask,
    const float* __restrict__ wc,
    float* __restrict__ out_ctx, float* __restrict__ out_w)
{
  __shared__ int   idxs[512];
  __shared__ float wls[2][512];     // raw acc per (q, slot); +INF = invalid
  __shared__ float wls2[512][2];    // final weights per slot, (q0,q1) pairs
  __shared__ int   cnt8[8];

  const int t    = threadIdx.x;
  const int lane = t & 63;
  const int w    = t >> 6;                 // 0..7
  const int b    = blockIdx.x & 7;
  const int qg   = blockIdx.x >> 3;
  const int rowbase = b * 128 + qg * 2;    // global q-row of q0

  // ---- setup: init LDS, zero out_w rows, mask compaction
  ((float*)wls)[t]        = 3.4e38f;
  ((float*)wls)[t + 512]  = 3.4e38f;
  ((float*)wls2)[t]       = 0.f;
  ((float*)wls2)[t + 512] = 0.f;
  idxs[t] = 0;
  if (t < 256) {
    float4 z = {0.f, 0.f, 0.f, 0.f};
    ((float4*)(out_w + (size_t)rowbase * 512))[t] = z;
  }
  const int mv = mask[b * 512 + t];
  const unsigned long long bal = __ballot(mv != 0);
  if (lane == 0) cnt8[w] = __popcll(bal);
  __syncthreads();
  int cnt = 0, offw = 0;
#pragma unroll
  for (int j = 0; j < 8; ++j) { if (j == w) offw = cnt; cnt += cnt8[j]; }
  if (mv) {
    int rank = __popcll(bal & ((1ull << lane) - 1ull));
    idxs[offw + rank] = t;
  }
  __syncthreads();

  // ---- score phase
  const int NSTEP = (cnt + 31) >> 5;       // 4-slot steps per wave (<=16)
  const int sbase = w * (NSTEP << 2);
  const int g  = lane >> 4;                // slot-group 0..3
  const int c4 = (lane & 15) << 2;         // h-quad base

  int   rows[16];
  float a0[16], a1[16];
#pragma unroll
  for (int i = 0; i < 16; ++i) {
    if (i >= NSTEP) break;
    rows[i] = idxs[sbase + (i << 2) + g];
    a0[i] = 0.f; a1[i] = 0.f;
  }

  const float* vpb = vp + (size_t)b * 512 * 512;
  const float* qr0 = qp + (size_t)rowbase * 512;
  const float* qr1 = qr0 + 512;

  for (int j = 0; j < 8; ++j) {
    const int hoff = j * 64 + c4;
    float4 q0v = *(const float4*)(qr0 + hoff);
    float4 q1v = *(const float4*)(qr1 + hoff);
    float4 wcv = *(const float4*)(wc + hoff);
    float cq0[4] = {C_SCALE * q0v.x, C_SCALE * q0v.y, C_SCALE * q0v.z, C_SCALE * q0v.w};
    float cq1[4] = {C_SCALE * q1v.x, C_SCALE * q1v.y, C_SCALE * q1v.z, C_SCALE * q1v.w};
    float wc4[4] = {wcv.x, wcv.y, wcv.z, wcv.w};

    float4 vcur = *(const float4*)(vpb + (size_t)rows[0] * 512 + hoff);
#pragma unroll
    for (int i = 0; i < 16; ++i) {
      if (i >= NSTEP) break;
      float4 vnext = vcur;
      if (i + 1 < NSTEP)
        vnext = *(const float4*)(vpb + (size_t)rows[i + 1] * 512 + hoff);
      float vv[4] = {vcur.x, vcur.y, vcur.z, vcur.w};
#pragma unroll
      for (int k = 0; k < 4; ++k) {
        float x0 = __builtin_fmaf(C_SCALE, vv[k], cq0[k]);
        float r0 = frcp(fexp2(x0) + 1.0f);
        a0[i] = __builtin_fmaf(wc4[k], r0, a0[i]);
        float x1 = __builtin_fmaf(C_SCALE, vv[k], cq1[k]);
        float r1 = frcp(fexp2(x1) + 1.0f);
        a1[i] = __builtin_fmaf(wc4[k], r1, a1[i]);
      }
      vcur = vnext;
    }
  }

  // per-slot reduce across the 16 lanes sharing g (xor 1,2,4,8), then write
#pragma unroll
  for (int i = 0; i < 16; ++i) {
    if (i >= NSTEP) break;
    float s0 = a0[i], s1 = a1[i];
#pragma unroll
    for (int off = 1; off < 16; off <<= 1) {
      s0 += __shfl_xor(s0, off, 64);
      s1 += __shfl_xor(s1, off, 64);
    }
    const int s = sbase + (i << 2) + g;
    if ((lane & 15) == i && s < cnt) { wls[0][s] = s0; wls[1][s] = s1; }
  }
  __syncthreads();

  // ---- softmax: waves 0-3 -> q0, 4-7 -> q1 (dup compute; waves 0/4 write)
  {
    const int mq = (w >= 4) ? 1 : 0;
    const float* sc = wls[mq];
    float4 u0 = ((const float4*)sc)[lane * 2];
    float4 u1 = ((const float4*)sc)[lane * 2 + 1];
    float s8[8] = {u0.x, u0.y, u0.z, u0.w, u1.x, u1.y, u1.z, u1.w};
    float m = s8[0];
#pragma unroll
    for (int k = 1; k < 8; ++k) m = fminf(m, s8[k]);      // min: weight=exp2(C*(m-s))
#pragma unroll
    for (int off = 1; off < 64; off <<= 1) m = fminf(m, __shfl_xor(m, off, 64));
    float e[8], S = 0.f;
#pragma unroll
    for (int k = 0; k < 8; ++k) { e[k] = fexp2(C_SCALE * (m - s8[k])); S += e[k]; }
#pragma unroll
    for (int off = 1; off < 64; off <<= 1) S += __shfl_xor(S, off, 64);
    const float rinv = frcp(S);
    if (w == 0 || w == 4) {
      float* owq = out_w + (size_t)(rowbase + mq) * 512;
#pragma unroll
      for (int k = 0; k < 8; ++k) {
        const int s = lane * 8 + k;
        const float wgt = e[k] * rinv;                    // invalid slots -> 0
        wls2[s][mq] = wgt;
        if (s < cnt) owq[idxs[s]] = wgt;
      }
    }
  }
  __syncthreads();

  // ---- context: wave w owns h-window [w*64, w*64+64)
  const int NC = (cnt + 3) >> 2;
  const int hbase = w * 64 + c4;
  const float* vb = values + (size_t)b * 512 * 512;
  float c0[4] = {0.f, 0.f, 0.f, 0.f}, c1[4] = {0.f, 0.f, 0.f, 0.f};
#pragma unroll 4
  for (int i = 0; i < NC; ++i) {
    const int s = (i << 2) + g;
    const int row = idxs[s];
    const float2 wg = *(const float2*)&wls2[s][0];        // padded slots: 0
    const float4 v4 = *(const float4*)(vb + (size_t)row * 512 + hbase);
    float vv[4] = {v4.x, v4.y, v4.z, v4.w};
#pragma unroll
    for (int k = 0; k < 4; ++k) {
      c0[k] = __builtin_fmaf(wg.x, vv[k], c0[k]);
      c1[k] = __builtin_fmaf(wg.y, vv[k], c1[k]);
    }
  }
#pragma unroll
  for (int k = 0; k < 4; ++k) {                           // reduce over g
    c0[k] += __shfl_xor(c0[k], 16, 64); c0[k] += __shfl_xor(c0[k], 32, 64);
    c1[k] += __shfl_xor(c1[k], 16, 64); c1[k] += __shfl_xor(c1[k], 32, 64);
  }
  if (lane < 16) {
    float4 o0 = {c0[0], c0[1], c0[2], c0[3]};
    float4 o1 = {c1[0], c1[1], c1[2], c1[3]};
    *(float4*)(out_ctx + (size_t)rowbase * 512 + w * 64 + lane * 4)       = o0;
    *(float4*)(out_ctx + (size_t)(rowbase + 1) * 512 + w * 64 + lane * 4) = o1;
  }
}

extern "C" void kernel_launch(void* const* d_in, const int* in_sizes, int n_in,
                              void* d_out, int out_size, void* d_ws, size_t ws_size,
                              hipStream_t stream) {
  const float* query  = (const float*)d_in[0];
  const float* values = (const float*)d_in[1];
  const int*   mask   = (const int*)d_in[2];
  const float* Wq     = (const float*)d_in[3];
  const float* bq     = (const float*)d_in[4];
  const float* Wv     = (const float*)d_in[5];
  const float* bv     = (const float*)d_in[6];
  const float* wc     = (const float*)d_in[7];
  // d_in[8] = bc: no effect on outputs (softmax shift-invariance) -> dropped.

  float* out = (float*)d_out;
  float* qp  = (float*)d_ws;                 // 1024 x 512
  float* vp  = qp + (size_t)1024 * 512;      // 4096 x 512

  proj_gemm_mfma<<<dim3(8, 80), 256, 0, stream>>>(query, values, Wq, Wv, bq, bv, qp, vp);
  attn_fused<<<512, 512, 0, stream>>>(qp, vp, values, mask, wc,
                                      out, out + (size_t)8 * 128 * 512);
}